// Round 1
// baseline (386.819 us; speedup 1.0000x reference)
//
#include <hip/hip_runtime.h>
#include <hip/hip_bf16.h>
#include <stdint.h>

// ---------------------------------------------------------------------------
// Block: LN -> [q,k,v,p] = h @ w_in^T -> key-smear -> causal attn w/ learned
// ALiBi -> o * silu(p) -> @ w_out^T -> LN.   B=2 L=2048 D=1024 H=16 Dh=128.
// Internal compute in bf16 MFMA (threshold 9.75e-2 allows it).
// ---------------------------------------------------------------------------

typedef __bf16 bf16;
typedef bf16  bf16x8 __attribute__((ext_vector_type(8)));
typedef float f32x4  __attribute__((ext_vector_type(4)));

#define SEQ   2048
#define NBATC 2

__device__ __forceinline__ void gld_lds16(const bf16* g, bf16* l) {
  __builtin_amdgcn_global_load_lds((const __attribute__((address_space(1))) void*)g,
                                   (__attribute__((address_space(3))) void*)l, 16, 0, 0);
}

// ---------------- f32 -> bf16 convert (8 elems/thread) ----------------------
__global__ __launch_bounds__(256) void cvt_kernel(const float* __restrict__ in,
                                                  bf16* __restrict__ out, int n8) {
  int t = blockIdx.x * 256 + threadIdx.x;
  if (t >= n8) return;
  const float4* p = (const float4*)in + (size_t)t * 2;
  float4 a = p[0], b = p[1];
  bf16x8 o;
  o[0] = (bf16)a.x; o[1] = (bf16)a.y; o[2] = (bf16)a.z; o[3] = (bf16)a.w;
  o[4] = (bf16)b.x; o[5] = (bf16)b.y; o[6] = (bf16)b.z; o[7] = (bf16)b.w;
  *((bf16x8*)out + t) = o;
}

// ---------------- LayerNorm over rows of 1024 f32 ---------------------------
template<bool BF16OUT>
__global__ __launch_bounds__(256) void ln_kernel(const float* __restrict__ x,
    const float* __restrict__ gamma, const float* __restrict__ beta,
    void* __restrict__ out) {
  const int row = blockIdx.x;
  const int tid = threadIdx.x;
  float4 v = *(const float4*)(x + (size_t)row * 1024 + tid * 4);
  float s  = v.x + v.y + v.z + v.w;
  float ss = v.x * v.x + v.y * v.y + v.z * v.z + v.w * v.w;
#pragma unroll
  for (int m = 1; m < 64; m <<= 1) { s += __shfl_xor(s, m, 64); ss += __shfl_xor(ss, m, 64); }
  __shared__ float red[8];
  if ((tid & 63) == 0) { red[tid >> 6] = s; red[(tid >> 6) + 4] = ss; }
  __syncthreads();
  s  = red[0] + red[1] + red[2] + red[3];
  ss = red[4] + red[5] + red[6] + red[7];
  const float mu  = s * (1.f / 1024.f);
  const float inv = rsqrtf(ss * (1.f / 1024.f) - mu * mu + 1e-5f);
  float4 g  = *(const float4*)(gamma + tid * 4);
  float4 bb = *(const float4*)(beta  + tid * 4);
  float y0 = (v.x - mu) * inv * g.x + bb.x;
  float y1 = (v.y - mu) * inv * g.y + bb.y;
  float y2 = (v.z - mu) * inv * g.z + bb.z;
  float y3 = (v.w - mu) * inv * g.w + bb.w;
  if (BF16OUT) {
    bf16* o = (bf16*)out + (size_t)row * 1024 + tid * 4;
    o[0] = (bf16)y0; o[1] = (bf16)y1; o[2] = (bf16)y2; o[3] = (bf16)y3;
  } else {
    float* o = (float*)out + (size_t)row * 1024 + tid * 4;
    o[0] = y0; o[1] = y1; o[2] = y2; o[3] = y3;
  }
}

// ---------------- key smear: ksm[b,h,i,:] = (1-s)k[i] + s k[i-1] ------------
__global__ __launch_bounds__(256) void smear_kernel(const bf16* __restrict__ qkvp,
    const float* __restrict__ smf, bf16* __restrict__ ksm) {
  int t  = blockIdx.x * 256 + threadIdx.x;   // 2^20 vec8 groups
  int d8 = t & 15;
  int i  = (t >> 4) & 2047;
  int h  = (t >> 15) & 15;
  int b  = t >> 19;
  float sm = 1.f / (1.f + __expf(-smf[h]));
  const bf16* base = qkvp + (size_t)(b * SEQ + i) * 8192 + 2048 + h * 128 + d8 * 8;
  bf16x8 cur = *(const bf16x8*)base;
  bf16x8 prv = cur;
  if (i > 0) prv = *(const bf16x8*)(base - 8192);
  bf16x8 o;
#pragma unroll
  for (int e = 0; e < 8; e++) {
    float pv = (i > 0) ? (float)prv[e] : 0.f;
    o[e] = (bf16)((1.f - sm) * (float)cur[e] + sm * pv);
  }
  *(bf16x8*)(ksm + ((size_t)(b * 16 + h) * SEQ + i) * 128 + d8 * 8) = o;
}

// ---------------- GEMM: C[M][N] = A[M][K] * Bt[N][K]^T  (bf16 MFMA) ---------
// 128x128 tile, BK=32, 4 waves (2x2), each wave 64x64 via 4x4 16x16x32 frags.
template<typename OutT>
__global__ __launch_bounds__(256) void gemm_bt(const bf16* __restrict__ A,
    const bf16* __restrict__ Bt, OutT* __restrict__ C, int M, int N, int K) {
  __shared__ bf16 As[128 * 32];
  __shared__ bf16 Bs[128 * 32];
  const int tid  = threadIdx.x;
  const int lane = tid & 63, wid = tid >> 6;
  const int l4 = lane >> 4, l16 = lane & 15;
  const int wr = wid >> 1, wc = wid & 1;
  const int rowBase = blockIdx.y * 128, colBase = blockIdx.x * 128;

  const bf16* gA = A  + (size_t)(rowBase + (tid >> 2)) * K + (tid & 3) * 8;
  const bf16* gB = Bt + (size_t)(colBase + (tid >> 2)) * K + (tid & 3) * 8;
  const size_t rowStep = (size_t)64 * K;

  f32x4 acc[4][4];
  const f32x4 z = {0.f, 0.f, 0.f, 0.f};
#pragma unroll
  for (int i = 0; i < 4; i++)
#pragma unroll
    for (int j = 0; j < 4; j++) acc[i][j] = z;

  for (int k0 = 0; k0 < K; k0 += 32) {
    __syncthreads();
    gld_lds16(gA + k0,           &As[tid * 8]);
    gld_lds16(gA + rowStep + k0, &As[2048 + tid * 8]);
    gld_lds16(gB + k0,           &Bs[tid * 8]);
    gld_lds16(gB + rowStep + k0, &Bs[2048 + tid * 8]);
    __syncthreads();
    bf16x8 af[4], bfr[4];
#pragma unroll
    for (int mi = 0; mi < 4; mi++)
      af[mi] = *(const bf16x8*)&As[(wr * 64 + mi * 16 + l16) * 32 + l4 * 8];
#pragma unroll
    for (int ni = 0; ni < 4; ni++)
      bfr[ni] = *(const bf16x8*)&Bs[(wc * 64 + ni * 16 + l16) * 32 + l4 * 8];
#pragma unroll
    for (int mi = 0; mi < 4; mi++)
#pragma unroll
      for (int ni = 0; ni < 4; ni++)
        acc[mi][ni] = __builtin_amdgcn_mfma_f32_16x16x32_bf16(af[mi], bfr[ni], acc[mi][ni], 0, 0, 0);
  }
#pragma unroll
  for (int mi = 0; mi < 4; mi++)
#pragma unroll
    for (int ni = 0; ni < 4; ni++) {
      int row = rowBase + wr * 64 + mi * 16 + l4 * 4;
      int col = colBase + wc * 64 + ni * 16 + l16;
#pragma unroll
      for (int r = 0; r < 4; r++)
        C[(size_t)(row + r) * N + col] = (OutT)acc[mi][ni][r];
    }
}

// ---------------- flash attention + ALiBi + causal + silu-gate --------------
// grid (32 q-tiles, 32 b*h). 4 waves x 16 q-rows. K-tile = 64.
__global__ __launch_bounds__(256) void attn_kernel(const bf16* __restrict__ qkvp,
    const bf16* __restrict__ ksm, const float* __restrict__ slopes,
    bf16* __restrict__ gated) {
  const int qt  = blockIdx.x;            // 0..31
  const int bh  = blockIdx.y;            // 0..31
  const int b   = bh >> 4, h = bh & 15;
  const int tid = threadIdx.x, wid = tid >> 6, lane = tid & 63;
  const int l4 = lane >> 4, l16 = lane & 15;
  const int qb = qt * 64;
  const float slope = slopes[h];
  const float scale = 0.08838834764831845f;  // 1/sqrt(128)

  __shared__ bf16 K_lds[64][136];   // +8 pad: stride 272B -> 2-way max
  __shared__ bf16 Vt_lds[128][72];  // V transposed, +8 pad
  __shared__ bf16 P_lds[64][72];    // P round-trip, +8 pad

  // Q fragments in registers (rows qb + wid*16 + l16)
  bf16x8 qf[4];
  {
    const bf16* qrow = qkvp + (size_t)(b * SEQ + qb + wid * 16 + l16) * 8192 + h * 128;
#pragma unroll
    for (int kb = 0; kb < 4; kb++) qf[kb] = *(const bf16x8*)(qrow + kb * 32 + l4 * 8);
  }

  f32x4 oacc[8];
  const f32x4 z = {0.f, 0.f, 0.f, 0.f};
#pragma unroll
  for (int i = 0; i < 8; i++) oacc[i] = z;
  float m_run[4], l_run[4];
#pragma unroll
  for (int r = 0; r < 4; r++) { m_run[r] = -1e30f; l_run[r] = 0.f; }

  const int ntiles = qt + 1;
  for (int kt = 0; kt < ntiles; ++kt) {
    __syncthreads();
    {  // stage K (natural) and V (transposed)
      int row = tid & 63;
      int dbase = (tid >> 6) * 8;
      const bf16* krow = ksm  + ((size_t)bh * SEQ + kt * 64 + row) * 128;
      const bf16* vrow = qkvp + (size_t)(b * SEQ + kt * 64 + row) * 8192 + 4096 + h * 128;
#pragma unroll
      for (int i2 = 0; i2 < 4; i2++) {
        int d0 = dbase + i2 * 32;
        *(bf16x8*)&K_lds[row][d0] = *(const bf16x8*)(krow + d0);
        bf16x8 v8 = *(const bf16x8*)(vrow + d0);
#pragma unroll
        for (int e = 0; e < 8; e++) Vt_lds[d0 + e][row] = v8[e];
      }
    }
    __syncthreads();

    // S = Q K^T  (per wave: 16 x 64)
    f32x4 sacc[4];
#pragma unroll
    for (int jf = 0; jf < 4; jf++) {
      f32x4 a = z;
#pragma unroll
      for (int kb = 0; kb < 4; kb++) {
        bf16x8 kf = *(const bf16x8*)&K_lds[jf * 16 + l16][kb * 32 + l4 * 8];
        a = __builtin_amdgcn_mfma_f32_16x16x32_bf16(qf[kb], kf, a, 0, 0, 0);
      }
      sacc[jf] = a;
    }

    // scale + alibi + causal mask
    const bool diag = (kt == qt);
    float sadj[4][4];
#pragma unroll
    for (int jf = 0; jf < 4; jf++) {
      int j = kt * 64 + jf * 16 + l16;
      float bias = (float)j * slope;
#pragma unroll
      for (int r = 0; r < 4; r++) {
        float v = sacc[jf][r] * scale + bias;
        if (diag) {
          int i = qb + wid * 16 + l4 * 4 + r;
          if (j > i) v = -1e30f;
        }
        sadj[jf][r] = v;
      }
    }

    // online softmax (rows live in 16-lane groups; reduce with shfl_xor 1..8)
    float p[4][4];
#pragma unroll
    for (int r = 0; r < 4; r++) {
      float mx = fmaxf(fmaxf(sadj[0][r], sadj[1][r]), fmaxf(sadj[2][r], sadj[3][r]));
#pragma unroll
      for (int m = 1; m < 16; m <<= 1) mx = fmaxf(mx, __shfl_xor(mx, m, 64));
      float mnew  = fmaxf(m_run[r], mx);
      float alpha = __expf(m_run[r] - mnew);
      float rowsum = 0.f;
#pragma unroll
      for (int jf = 0; jf < 4; jf++) {
        float pe = __expf(sadj[jf][r] - mnew);
        p[jf][r] = pe;
        rowsum += pe;
      }
#pragma unroll
      for (int m = 1; m < 16; m <<= 1) rowsum += __shfl_xor(rowsum, m, 64);
      l_run[r] = l_run[r] * alpha + rowsum;
      m_run[r] = mnew;
#pragma unroll
      for (int df = 0; df < 8; df++) oacc[df][r] *= alpha;
    }

    // P -> LDS (per-wave private rows), then PV via MFMA
#pragma unroll
    for (int jf = 0; jf < 4; jf++)
#pragma unroll
      for (int r = 0; r < 4; r++)
        P_lds[wid * 16 + l4 * 4 + r][jf * 16 + l16] = (bf16)p[jf][r];

#pragma unroll
    for (int kb2 = 0; kb2 < 2; ++kb2) {
      bf16x8 pf = *(const bf16x8*)&P_lds[wid * 16 + l16][kb2 * 32 + l4 * 8];
#pragma unroll
      for (int df = 0; df < 8; df++) {
        bf16x8 vf = *(const bf16x8*)&Vt_lds[df * 16 + l16][kb2 * 32 + l4 * 8];
        oacc[df] = __builtin_amdgcn_mfma_f32_16x16x32_bf16(pf, vf, oacc[df], 0, 0, 0);
      }
    }
  }

  // epilogue: normalize, gate with silu(p), store bf16
#pragma unroll
  for (int df = 0; df < 8; df++) {
    int d = df * 16 + l16;
#pragma unroll
    for (int r = 0; r < 4; r++) {
      int i = qb + wid * 16 + l4 * 4 + r;
      float o = oacc[df][r] / l_run[r];
      float pg = (float)qkvp[(size_t)(b * SEQ + i) * 8192 + 6144 + h * 128 + d];
      float silu = pg / (1.f + __expf(-pg));
      gated[(size_t)(b * SEQ + i) * 2048 + h * 128 + d] = (bf16)(silu * o);
    }
  }
}

// ---------------------------------------------------------------------------
extern "C" void kernel_launch(void* const* d_in, const int* in_sizes, int n_in,
                              void* d_out, int out_size, void* d_ws, size_t ws_size,
                              hipStream_t stream) {
  (void)in_sizes; (void)n_in; (void)out_size; (void)ws_size;
  const float* x      = (const float*)d_in[0];
  const float* w_in   = (const float*)d_in[1];
  const float* w_out  = (const float*)d_in[2];
  const float* lnig   = (const float*)d_in[3];
  const float* lnib   = (const float*)d_in[4];
  const float* lnog   = (const float*)d_in[5];
  const float* lnob   = (const float*)d_in[6];
  const float* slopes = (const float*)d_in[7];
  const float* smf    = (const float*)d_in[8];
  float* out = (float*)d_out;

  char* ws = (char*)d_ws;
  size_t off = 0;
  bf16* hb      = (bf16*)(ws + off); off += (size_t)4096 * 1024 * 2;  // h (bf16)
  bf16* w_in_b  = (bf16*)(ws + off); off += (size_t)8192 * 1024 * 2;
  bf16* w_out_b = (bf16*)(ws + off); off += (size_t)1024 * 2048 * 2;
  bf16* qkvp    = (bf16*)(ws + off); off += (size_t)4096 * 8192 * 2;
  bf16* ksm     = (bf16*)(ws + off); off += (size_t)32 * 2048 * 128 * 2;
  bf16* gated   = (bf16*)(ws + off); off += (size_t)4096 * 2048 * 2;
  float* yb     = (float*)(ws + off); off += (size_t)4096 * 1024 * 4;

  cvt_kernel<<<4096, 256, 0, stream>>>(w_in,  w_in_b,  8388608 / 8);
  cvt_kernel<<<1024, 256, 0, stream>>>(w_out, w_out_b, 2097152 / 8);
  ln_kernel<true><<<4096, 256, 0, stream>>>(x, lnig, lnib, hb);
  gemm_bt<bf16><<<dim3(64, 32), 256, 0, stream>>>(hb, w_in_b, qkvp, 4096, 8192, 1024);
  smear_kernel<<<4096, 256, 0, stream>>>(qkvp, smf, ksm);
  attn_kernel<<<dim3(32, 32), 256, 0, stream>>>(qkvp, ksm, slopes, gated);
  gemm_bt<float><<<dim3(8, 32), 256, 0, stream>>>(gated, w_out_b, yb, 4096, 1024, 2048);
  ln_kernel<false><<<4096, 256, 0, stream>>>(yb, lnog, lnob, out);
}

// Round 2
// 284.495 us; speedup vs baseline: 1.3597x; 1.3597x over previous
//
#include <hip/hip_runtime.h>
#include <hip/hip_bf16.h>
#include <stdint.h>

// ---------------------------------------------------------------------------
// Block: LN -> [q,k,v,p] = h @ w_in^T -> key-smear -> causal attn w/ learned
// ALiBi -> o * silu(p) -> @ w_out^T -> LN.   B=2 L=2048 D=1024 H=16 Dh=128.
// Internal compute in bf16 MFMA.
// ---------------------------------------------------------------------------

typedef __bf16 bf16;
typedef bf16  bf16x8 __attribute__((ext_vector_type(8)));
typedef float f32x4  __attribute__((ext_vector_type(4)));

#define SEQ   2048
#define NBATC 2

__device__ __forceinline__ void gld_lds16(const bf16* g, bf16* l) {
  __builtin_amdgcn_global_load_lds((const __attribute__((address_space(1))) void*)g,
                                   (__attribute__((address_space(3))) void*)l, 16, 0, 0);
}

// ---------------- f32 -> bf16 convert (8 elems/thread) ----------------------
__global__ __launch_bounds__(256) void cvt_kernel(const float* __restrict__ in,
                                                  bf16* __restrict__ out, int n8) {
  int t = blockIdx.x * 256 + threadIdx.x;
  if (t >= n8) return;
  const float4* p = (const float4*)in + (size_t)t * 2;
  float4 a = p[0], b = p[1];
  bf16x8 o;
  o[0] = (bf16)a.x; o[1] = (bf16)a.y; o[2] = (bf16)a.z; o[3] = (bf16)a.w;
  o[4] = (bf16)b.x; o[5] = (bf16)b.y; o[6] = (bf16)b.z; o[7] = (bf16)b.w;
  *((bf16x8*)out + t) = o;
}

// ---------------- LayerNorm over rows of 1024 f32 ---------------------------
template<bool BF16OUT>
__global__ __launch_bounds__(256) void ln_kernel(const float* __restrict__ x,
    const float* __restrict__ gamma, const float* __restrict__ beta,
    void* __restrict__ out) {
  const int row = blockIdx.x;
  const int tid = threadIdx.x;
  float4 v = *(const float4*)(x + (size_t)row * 1024 + tid * 4);
  float s  = v.x + v.y + v.z + v.w;
  float ss = v.x * v.x + v.y * v.y + v.z * v.z + v.w * v.w;
#pragma unroll
  for (int m = 1; m < 64; m <<= 1) { s += __shfl_xor(s, m, 64); ss += __shfl_xor(ss, m, 64); }
  __shared__ float red[8];
  if ((tid & 63) == 0) { red[tid >> 6] = s; red[(tid >> 6) + 4] = ss; }
  __syncthreads();
  s  = red[0] + red[1] + red[2] + red[3];
  ss = red[4] + red[5] + red[6] + red[7];
  const float mu  = s * (1.f / 1024.f);
  const float inv = rsqrtf(ss * (1.f / 1024.f) - mu * mu + 1e-5f);
  float4 g  = *(const float4*)(gamma + tid * 4);
  float4 bb = *(const float4*)(beta  + tid * 4);
  float y0 = (v.x - mu) * inv * g.x + bb.x;
  float y1 = (v.y - mu) * inv * g.y + bb.y;
  float y2 = (v.z - mu) * inv * g.z + bb.z;
  float y3 = (v.w - mu) * inv * g.w + bb.w;
  if (BF16OUT) {
    bf16* o = (bf16*)out + (size_t)row * 1024 + tid * 4;
    o[0] = (bf16)y0; o[1] = (bf16)y1; o[2] = (bf16)y2; o[3] = (bf16)y3;
  } else {
    float* o = (float*)out + (size_t)row * 1024 + tid * 4;
    o[0] = y0; o[1] = y1; o[2] = y2; o[3] = y3;
  }
}

// ---------------- key smear -> ksm, stored XOR-swizzled ---------------------
// ksm[bh][i][d] physical element index: row*128 + ((d) ^ ((i&7)<<3)) on 8-elem
// groups, so linear global_load_lds of a 64x128 tile yields swizzled LDS.
__global__ __launch_bounds__(256) void smear_kernel(const bf16* __restrict__ qkvp,
    const float* __restrict__ smf, bf16* __restrict__ ksm) {
  int t  = blockIdx.x * 256 + threadIdx.x;   // 2^20 vec8 groups
  int d8 = t & 15;
  int i  = (t >> 4) & 2047;
  int h  = (t >> 15) & 15;
  int b  = t >> 19;
  float sm = 1.f / (1.f + __expf(-smf[h]));
  const bf16* base = qkvp + (size_t)(b * SEQ + i) * 8192 + 2048 + h * 128 + d8 * 8;
  bf16x8 cur = *(const bf16x8*)base;
  bf16x8 prv = cur;
  if (i > 0) prv = *(const bf16x8*)(base - 8192);
  bf16x8 o;
#pragma unroll
  for (int e = 0; e < 8; e++) {
    float pv = (i > 0) ? (float)prv[e] : 0.f;
    o[e] = (bf16)((1.f - sm) * (float)cur[e] + sm * pv);
  }
  size_t idx = ((size_t)(b * 16 + h) * SEQ + i) * 128 + ((d8 * 8) ^ ((i & 7) << 3));
  *(bf16x8*)(ksm + idx) = o;
}

// ---------------- V transpose: vt[bh][kt][d][i0..63], XOR-swizzled ----------
__global__ __launch_bounds__(256) void vtrans_kernel(const bf16* __restrict__ qkvp,
                                                     bf16* __restrict__ vt) {
  __shared__ bf16 T[128][72];
  const int kt = blockIdx.x, bh = blockIdx.y;
  const int b = bh >> 4, h = bh & 15;
  const int t = threadIdx.x;
  {
    int i = t >> 2, d0 = (t & 3) * 32;
    const bf16* src = qkvp + (size_t)(b * SEQ + kt * 64 + i) * 8192 + 4096 + h * 128 + d0;
#pragma unroll
    for (int m = 0; m < 4; m++) {
      bf16x8 v8 = *(const bf16x8*)(src + m * 8);
#pragma unroll
      for (int e = 0; e < 8; e++) T[d0 + m * 8 + e][i] = v8[e];
    }
  }
  __syncthreads();
  {
    int d = t >> 1, i0 = (t & 1) * 32;
    bf16* dst = vt + (size_t)bh * (SEQ * 128) + (size_t)kt * 8192 + d * 64;
#pragma unroll
    for (int m = 0; m < 4; m++) {
      bf16x8 v8 = *(const bf16x8*)&T[d][i0 + m * 8];
      *(bf16x8*)(dst + (((i0 + m * 8)) ^ ((d & 7) << 3))) = v8;
    }
  }
}

// ---------------- GEMM: C[M][N] = A[M][K] * Bt[N][K]^T  (bf16 MFMA) ---------
template<typename OutT>
__global__ __launch_bounds__(256) void gemm_bt(const bf16* __restrict__ A,
    const bf16* __restrict__ Bt, OutT* __restrict__ C, int M, int N, int K) {
  __shared__ bf16 As[128 * 32];
  __shared__ bf16 Bs[128 * 32];
  const int tid  = threadIdx.x;
  const int lane = tid & 63, wid = tid >> 6;
  const int l4 = lane >> 4, l16 = lane & 15;
  const int wr = wid >> 1, wc = wid & 1;
  const int rowBase = blockIdx.y * 128, colBase = blockIdx.x * 128;

  const bf16* gA = A  + (size_t)(rowBase + (tid >> 2)) * K + (tid & 3) * 8;
  const bf16* gB = Bt + (size_t)(colBase + (tid >> 2)) * K + (tid & 3) * 8;
  const size_t rowStep = (size_t)64 * K;

  f32x4 acc[4][4];
  const f32x4 z = {0.f, 0.f, 0.f, 0.f};
#pragma unroll
  for (int i = 0; i < 4; i++)
#pragma unroll
    for (int j = 0; j < 4; j++) acc[i][j] = z;

  for (int k0 = 0; k0 < K; k0 += 32) {
    __syncthreads();
    gld_lds16(gA + k0,           &As[tid * 8]);
    gld_lds16(gA + rowStep + k0, &As[2048 + tid * 8]);
    gld_lds16(gB + k0,           &Bs[tid * 8]);
    gld_lds16(gB + rowStep + k0, &Bs[2048 + tid * 8]);
    __syncthreads();
    bf16x8 af[4], bfr[4];
#pragma unroll
    for (int mi = 0; mi < 4; mi++)
      af[mi] = *(const bf16x8*)&As[(wr * 64 + mi * 16 + l16) * 32 + l4 * 8];
#pragma unroll
    for (int ni = 0; ni < 4; ni++)
      bfr[ni] = *(const bf16x8*)&Bs[(wc * 64 + ni * 16 + l16) * 32 + l4 * 8];
#pragma unroll
    for (int mi = 0; mi < 4; mi++)
#pragma unroll
      for (int ni = 0; ni < 4; ni++)
        acc[mi][ni] = __builtin_amdgcn_mfma_f32_16x16x32_bf16(af[mi], bfr[ni], acc[mi][ni], 0, 0, 0);
  }
#pragma unroll
  for (int mi = 0; mi < 4; mi++)
#pragma unroll
    for (int ni = 0; ni < 4; ni++) {
      int row = rowBase + wr * 64 + mi * 16 + l4 * 4;
      int col = colBase + wc * 64 + ni * 16 + l16;
#pragma unroll
      for (int r = 0; r < 4; r++)
        C[(size_t)(row + r) * N + col] = (OutT)acc[mi][ni][r];
    }
}

// ---------------- flash attention + ALiBi + causal + silu-gate --------------
// Block handles q-tile pair (qp, 31-qp): uniform 33 K-tiles per block.
// K/V staged via global_load_lds from pre-swizzled global layouts,
// double-buffered (prefetch t+1 overlaps compute t).
__global__ __launch_bounds__(256) void attn_kernel(const bf16* __restrict__ qkvp,
    const bf16* __restrict__ ksm, const bf16* __restrict__ vt,
    const float* __restrict__ slopes, bf16* __restrict__ gated) {
  const int qp  = blockIdx.x;            // 0..15
  const int bh  = blockIdx.y;            // 0..31
  const int b   = bh >> 4, h = bh & 15;
  const int tid = threadIdx.x, wid = tid >> 6, lane = tid & 63;
  const int l4 = lane >> 4, l16 = lane & 15;
  const float slope = slopes[h];
  const float scale = 0.08838834764831845f;  // 1/sqrt(128)

  __shared__ bf16 Kb[2][64 * 128];
  __shared__ bf16 Vb[2][64 * 128];
  __shared__ bf16 P_lds[64][72];

  const bf16* ksmB = ksm + (size_t)bh * SEQ * 128;
  const bf16* vtB  = vt  + (size_t)bh * SEQ * 128;

  auto stage = [&](int kt, int bsel) {
    const bf16* ks = ksmB + kt * 8192 + tid * 8;
    const bf16* vs = vtB  + kt * 8192 + tid * 8;
    bf16* kd = &Kb[bsel][tid * 8];
    bf16* vd = &Vb[bsel][tid * 8];
#pragma unroll
    for (int g = 0; g < 4; g++) {
      gld_lds16(ks + g * 2048, kd + g * 2048);
      gld_lds16(vs + g * 2048, vd + g * 2048);
    }
  };

  auto run_strip = [&](int qtile, int ntiles) {
    // Q fragments (rows qtile*64 + wid*16 + l16)
    bf16x8 qf[4];
    {
      const bf16* qrow = qkvp + (size_t)(b * SEQ + qtile * 64 + wid * 16 + l16) * 8192 + h * 128;
#pragma unroll
      for (int kb = 0; kb < 4; kb++) qf[kb] = *(const bf16x8*)(qrow + kb * 32 + l4 * 8);
    }
    f32x4 oacc[8];
    const f32x4 z = {0.f, 0.f, 0.f, 0.f};
#pragma unroll
    for (int i = 0; i < 8; i++) oacc[i] = z;
    float m_run[4], l_run[4];
#pragma unroll
    for (int r = 0; r < 4; r++) { m_run[r] = -1e30f; l_run[r] = 0.f; }

    stage(0, 0);
    for (int t = 0; t < ntiles; ++t) {
      __syncthreads();                     // drains tile-t loads (vmcnt)
      if (t + 1 < ntiles) stage(t + 1, (t + 1) & 1);   // prefetch overlaps compute
      const bf16* K_ = Kb[t & 1];
      const bf16* V_ = Vb[t & 1];
      const int kt = t;

      // S = Q K^T  (per wave: 16 x 64), swizzled reads
      f32x4 sacc[4];
#pragma unroll
      for (int jf = 0; jf < 4; jf++) {
        f32x4 a = z;
        const int row = jf * 16 + l16;
#pragma unroll
        for (int kb = 0; kb < 4; kb++) {
          bf16x8 kf = *(const bf16x8*)&K_[row * 128 + ((kb * 32 + l4 * 8) ^ ((row & 7) << 3))];
          a = __builtin_amdgcn_mfma_f32_16x16x32_bf16(qf[kb], kf, a, 0, 0, 0);
        }
        sacc[jf] = a;
      }

      // scale + alibi + causal mask
      const bool diag = (kt == qtile);
      float sadj[4][4];
#pragma unroll
      for (int jf = 0; jf < 4; jf++) {
        int j = kt * 64 + jf * 16 + l16;
        float bias = (float)j * slope;
#pragma unroll
        for (int r = 0; r < 4; r++) {
          float v = sacc[jf][r] * scale + bias;
          if (diag) {
            int i = qtile * 64 + wid * 16 + l4 * 4 + r;
            if (j > i) v = -1e30f;
          }
          sadj[jf][r] = v;
        }
      }

      // online softmax (row j-values live across 16 lanes x 4 regs)
      float p[4][4];
#pragma unroll
      for (int r = 0; r < 4; r++) {
        float mx = fmaxf(fmaxf(sadj[0][r], sadj[1][r]), fmaxf(sadj[2][r], sadj[3][r]));
#pragma unroll
        for (int m = 1; m < 16; m <<= 1) mx = fmaxf(mx, __shfl_xor(mx, m, 64));
        float mnew  = fmaxf(m_run[r], mx);
        float alpha = __expf(m_run[r] - mnew);
        float rowsum = 0.f;
#pragma unroll
        for (int jf = 0; jf < 4; jf++) {
          float pe = __expf(sadj[jf][r] - mnew);
          p[jf][r] = pe;
          rowsum += pe;
        }
#pragma unroll
        for (int m = 1; m < 16; m <<= 1) rowsum += __shfl_xor(rowsum, m, 64);
        l_run[r] = l_run[r] * alpha + rowsum;
        m_run[r] = mnew;
#pragma unroll
        for (int df = 0; df < 8; df++) oacc[df][r] *= alpha;
      }

      // P -> LDS (per-wave private rows), then PV via MFMA (swizzled V reads)
#pragma unroll
      for (int jf = 0; jf < 4; jf++)
#pragma unroll
        for (int r = 0; r < 4; r++)
          P_lds[wid * 16 + l4 * 4 + r][jf * 16 + l16] = (bf16)p[jf][r];

#pragma unroll
      for (int kb2 = 0; kb2 < 2; ++kb2) {
        bf16x8 pf = *(const bf16x8*)&P_lds[wid * 16 + l16][kb2 * 32 + l4 * 8];
#pragma unroll
        for (int df = 0; df < 8; df++) {
          const int d = df * 16 + l16;
          bf16x8 vf = *(const bf16x8*)&V_[d * 64 + ((kb2 * 32 + l4 * 8) ^ ((d & 7) << 3))];
          oacc[df] = __builtin_amdgcn_mfma_f32_16x16x32_bf16(pf, vf, oacc[df], 0, 0, 0);
        }
      }
    }

    // epilogue: normalize, gate with silu(p), store bf16
#pragma unroll
    for (int df = 0; df < 8; df++) {
      int d = df * 16 + l16;
#pragma unroll
      for (int r = 0; r < 4; r++) {
        int i = qtile * 64 + wid * 16 + l4 * 4 + r;
        float o = oacc[df][r] / l_run[r];
        float pg = (float)qkvp[(size_t)(b * SEQ + i) * 8192 + 6144 + h * 128 + d];
        float silu = pg / (1.f + __expf(-pg));
        gated[(size_t)(b * SEQ + i) * 2048 + h * 128 + d] = (bf16)(silu * o);
      }
    }
  };

  run_strip(qp, qp + 1);
  __syncthreads();        // protect Kb[0]/Vb[0] before strip B's prologue stage
  run_strip(31 - qp, 32 - qp);
}

// ---------------------------------------------------------------------------
extern "C" void kernel_launch(void* const* d_in, const int* in_sizes, int n_in,
                              void* d_out, int out_size, void* d_ws, size_t ws_size,
                              hipStream_t stream) {
  (void)in_sizes; (void)n_in; (void)out_size; (void)ws_size;
  const float* x      = (const float*)d_in[0];
  const float* w_in   = (const float*)d_in[1];
  const float* w_out  = (const float*)d_in[2];
  const float* lnig   = (const float*)d_in[3];
  const float* lnib   = (const float*)d_in[4];
  const float* lnog   = (const float*)d_in[5];
  const float* lnob   = (const float*)d_in[6];
  const float* slopes = (const float*)d_in[7];
  const float* smf    = (const float*)d_in[8];
  float* out = (float*)d_out;

  char* ws = (char*)d_ws;
  size_t off = 0;
  bf16* hb      = (bf16*)(ws + off); off += (size_t)4096 * 1024 * 2;  // h (bf16)
  bf16* w_in_b  = (bf16*)(ws + off); off += (size_t)8192 * 1024 * 2;
  bf16* w_out_b = (bf16*)(ws + off); off += (size_t)1024 * 2048 * 2;
  bf16* qkvp    = (bf16*)(ws + off); off += (size_t)4096 * 8192 * 2;
  bf16* ksm     = (bf16*)(ws + off); off += (size_t)32 * 2048 * 128 * 2;
  bf16* gated   = (bf16*)(ws + off); off += (size_t)4096 * 2048 * 2;
  float* yb     = (float*)(ws + off); off += (size_t)4096 * 1024 * 4;
  bf16* vt      = (bf16*)yb;  // alias: vt dead before gemm2 writes yb

  cvt_kernel<<<4096, 256, 0, stream>>>(w_in,  w_in_b,  8388608 / 8);
  cvt_kernel<<<1024, 256, 0, stream>>>(w_out, w_out_b, 2097152 / 8);
  ln_kernel<true><<<4096, 256, 0, stream>>>(x, lnig, lnib, hb);
  gemm_bt<bf16><<<dim3(64, 32), 256, 0, stream>>>(hb, w_in_b, qkvp, 4096, 8192, 1024);
  smear_kernel<<<4096, 256, 0, stream>>>(qkvp, smf, ksm);
  vtrans_kernel<<<dim3(32, 32), 256, 0, stream>>>(qkvp, vt);
  attn_kernel<<<dim3(16, 32), 256, 0, stream>>>(qkvp, ksm, vt, slopes, gated);
  gemm_bt<float><<<dim3(8, 32), 256, 0, stream>>>(gated, w_out_b, yb, 4096, 1024, 2048);
  ln_kernel<false><<<4096, 256, 0, stream>>>(yb, lnog, lnob, out);
}